// Round 1
// baseline (316.475 us; speedup 1.0000x reference)
//
#include <hip/hip_runtime.h>
#include <hip/hip_bf16.h>
#include <stdint.h>

#define NB 2
#define NS 2048
#define NE 1024
#define NH 16
#define ND 64
#define N3 3072

typedef __attribute__((ext_vector_type(8))) short s16x8;
typedef __attribute__((ext_vector_type(4))) short s16x4;
typedef __attribute__((ext_vector_type(4))) float f32x4;

__device__ __forceinline__ float bf2f(short u){
  union { unsigned int i; float f; } v; v.i = ((unsigned int)(unsigned short)u) << 16; return v.f;
}
__device__ __forceinline__ short f2bf(float f){
  union { float f; unsigned int i; } v; v.f = f;
  unsigned int r = (v.i + 0x7fffu + ((v.i >> 16) & 1u)) >> 16;
  return (short)(unsigned short)r;
}
__device__ __forceinline__ f32x4 mfma16(s16x8 a, s16x8 b, f32x4 c){
  return __builtin_amdgcn_mfma_f32_16x16x32_bf16(a, b, c, 0, 0, 0);
}
__device__ __forceinline__ void load_lds16(const void* g, void* l){
  __builtin_amdgcn_global_load_lds(
      (const __attribute__((address_space(1))) unsigned int*)g,
      (__attribute__((address_space(3))) unsigned int*)l, 16, 0, 0);
}

// ---------------- fp32 -> bf16 convert (vectorized) ----------------
__global__ void k_cvt(const float* __restrict__ in, short* __restrict__ out, int n4){
  int i = blockIdx.x * blockDim.x + threadIdx.x;
  if (i >= n4) return;
  float4 v = ((const float4*)in)[i];
  s16x4 o = { f2bf(v.x), f2bf(v.y), f2bf(v.z), f2bf(v.w) };
  *(s16x4*)(out + (size_t)i*4) = o;
}

// ---------------- fp32 [R][C] -> bf16 [C][R] transpose ----------------
__global__ void k_tcvt(const float* __restrict__ in, short* __restrict__ out, int R, int C){
  __shared__ float t[32][33];
  int c0 = blockIdx.x*32, r0 = blockIdx.y*32;
  int tx = threadIdx.x, ty = threadIdx.y;
  #pragma unroll
  for (int i=0;i<4;++i){
    int r = r0 + ty + i*8;
    t[ty + i*8][tx] = in[(size_t)r*C + c0 + tx];
  }
  __syncthreads();
  #pragma unroll
  for (int i=0;i<4;++i){
    int cc = c0 + ty + i*8;
    out[(size_t)cc*R + r0 + tx] = f2bf(t[tx][ty + i*8]);
  }
}

// ---------------- bf16 GEMM: C[M][N] = A[M][K] * Bt[N][K]^T + bias ----------------
// 128x128 tile, BK=64, global_load_lds(16B) with G4 XOR-swizzle via pre-swizzled
// global source (LDS dest stays linear, read applies the same XOR).
template<int OUTF32>
__global__ __launch_bounds__(256) void k_gemm(const short* __restrict__ A,
    const short* __restrict__ Bt, const float* __restrict__ bias,
    short* __restrict__ outB, float* __restrict__ outF, int M, int N, int K)
{
  __shared__ short lds[128*64*2];   // A tile [128][64] then B tile [128][64]
  const int tid = threadIdx.x;
  const int lane = tid & 63, w = tid >> 6;
  const int g = lane >> 4, c = lane & 15;
  const int wm = (w >> 1) * 64, wn = (w & 1) * 64;
  const int bm = blockIdx.x * 128, bn = blockIdx.y * 128;

  f32x4 acc[4][4];
  #pragma unroll
  for (int i=0;i<4;++i)
    #pragma unroll
    for (int j=0;j<4;++j) acc[i][j] = (f32x4){0.f,0.f,0.f,0.f};

  const int nkt = K >> 6;
  for (int kt = 0; kt < nkt; ++kt){
    __syncthreads();
    #pragma unroll
    for (int i = 0; i < 8; ++i){
      const int seg   = w*8 + i;          // 0..31 ; segs 0-15 = A, 16-31 = B
      const int chunk = seg*64 + lane;    // 16-byte units
      const int local = chunk & 1023;
      const int row = local >> 3, kc = local & 7;
      const short* base = (chunk < 1024)
        ? (A  + (size_t)(bm + row) * K + kt*64)
        : (Bt + (size_t)(bn + row) * K + kt*64);
      const char* gaddr = (const char*)base + ((kc*16) ^ ((row & 7) << 4));
      load_lds16(gaddr, (char*)lds + seg*1024);
    }
    asm volatile("s_waitcnt vmcnt(0)" ::: "memory");
    __syncthreads();
    #pragma unroll
    for (int kk = 0; kk < 2; ++kk){
      s16x8 af[4], bfr[4];
      #pragma unroll
      for (int mi = 0; mi < 4; ++mi){
        int m = wm + mi*16 + c;
        int kb = (kk*64 + g*16) ^ ((m & 7) << 4);
        af[mi] = *(const s16x8*)((const char*)lds + m*128 + kb);
      }
      #pragma unroll
      for (int ni = 0; ni < 4; ++ni){
        int n = wn + ni*16 + c;
        int kb = (kk*64 + g*16) ^ ((n & 7) << 4);
        bfr[ni] = *(const s16x8*)((const char*)lds + 16384 + n*128 + kb);
      }
      #pragma unroll
      for (int mi = 0; mi < 4; ++mi)
        #pragma unroll
        for (int ni = 0; ni < 4; ++ni)
          acc[mi][ni] = mfma16(af[mi], bfr[ni], acc[mi][ni]);
    }
  }
  #pragma unroll
  for (int mi = 0; mi < 4; ++mi){
    #pragma unroll
    for (int ni = 0; ni < 4; ++ni){
      int col = bn + wn + ni*16 + c;
      float bv = bias[col];
      #pragma unroll
      for (int j = 0; j < 4; ++j){
        int rrow = bm + wm + mi*16 + g*4 + j;   // C/D: col=lane&15, row=4*(lane>>4)+j
        float v = acc[mi][ni][j] + bv;
        if (OUTF32) outF[(size_t)rrow * N + col] = v;
        else        outB[(size_t)rrow * N + col] = f2bf(v);
      }
    }
  }
}

// ---------------- RoPE on q,k parts of QKV -> Qr/Kr [B][H][S][D] ----------------
__global__ void k_rope(const short* __restrict__ qkv, short* __restrict__ Qr,
                       short* __restrict__ Kr){
  int idx = blockIdx.x * 256 + threadIdx.x;   // B*S*H*32 = 2,097,152
  int i = idx & 31;
  int h = (idx >> 5) & 15;
  int s = (idx >> 9) & 2047;
  int b = idx >> 20;
  float inv = __builtin_amdgcn_exp2f(-(float)i * (13.287712379549449f / 32.0f)); // 10000^(-i/32)
  float ang = (float)s * inv;
  float cs = cosf(ang), sn = sinf(ang);
  size_t base = (size_t)(b*NS + s) * N3 + h*ND + 2*i;
  float x0 = bf2f(qkv[base]),      x1 = bf2f(qkv[base+1]);
  float y0 = bf2f(qkv[base+1024]), y1 = bf2f(qkv[base+1025]);
  size_t ob = ((size_t)(b*NH + h)*NS + s) * ND + 2*i;
  Qr[ob]   = f2bf(x0*cs - x1*sn);
  Qr[ob+1] = f2bf(x1*cs + x0*sn);
  Kr[ob]   = f2bf(y0*cs - y1*sn);
  Kr[ob+1] = f2bf(y1*cs + y0*sn);
}

// ---------------- V part of QKV -> Vt [B][H][D][S] (transposed) ----------------
__global__ void k_vtrans(const short* __restrict__ qkv, short* __restrict__ Vt){
  __shared__ short t[64][72];
  const int bid = blockIdx.x;                 // B*H*(S/64) = 1024
  const int sb = bid & 31, h = (bid>>5) & 15, b = bid >> 9;
  const int s0 = sb * 64;
  const int tid = threadIdx.x;
  #pragma unroll
  for (int it=0; it<2; ++it){
    int u = it*256 + tid;
    int r = u >> 3, cc = (u & 7) * 8;
    s16x8 v = *(const s16x8*)(qkv + (size_t)(b*NS + s0 + r)*N3 + 2048 + h*ND + cc);
    *(s16x8*)&t[r][cc] = v;
  }
  __syncthreads();
  #pragma unroll
  for (int it=0; it<2; ++it){
    int u = it*256 + tid;
    int d = u >> 3, sc2 = (u & 7) * 8;
    s16x8 v;
    #pragma unroll
    for (int j=0;j<8;++j) v[j] = t[sc2 + j][d];
    *(s16x8*)(Vt + ((size_t)(b*NH + h)*ND + d)*NS + s0 + sc2) = v;
  }
}

// ---------------- causal flash attention ----------------
// 4 waves/block, 16 q rows/wave, KBLK=32. Swapped QK^T: S^T = mfma(K, Q) so the
// softmax k-reduction is shfl_xor(16/32) + in-register. P relayout via per-wave LDS.
__global__ __launch_bounds__(256) void k_attn(const short* __restrict__ Qr,
    const short* __restrict__ Kr, const short* __restrict__ Vt,
    short* __restrict__ Obuf)
{
  __shared__ short plds[4][16*40];            // per-wave P tile [16 q][32 k] padded
  const int tid = threadIdx.x;
  const int lane = tid & 63, w = tid >> 6;
  const int g = lane >> 4, c = lane & 15;
  const int bid = blockIdx.x;                 // B*H*(S/64) = 1024
  const int qb = bid & 31;
  const int h = (bid >> 5) & 15;
  const int b = bid >> 9;
  const int q0 = qb*64 + w*16;
  const size_t bh = (size_t)(b*NH + h);
  const short* Qbh = Qr + bh * (NS*ND);
  const short* Kbh = Kr + bh * (NS*ND);
  const short* Vbh = Vt + bh * (ND*NS);
  short* pw = &plds[w][0];

  s16x8 qf[2];
  {
    const short* qp = Qbh + (size_t)(q0 + c) * ND + g*8;
    qf[0] = *(const s16x8*)(qp);
    qf[1] = *(const s16x8*)(qp + 32);
  }
  f32x4 acc[4];
  #pragma unroll
  for (int dt=0; dt<4; ++dt) acc[dt] = (f32x4){0.f,0.f,0.f,0.f};
  float mrow = -3.0e38f, lrow = 0.f;
  const float sc = 0.125f * 1.44269504088896340736f;  // scale * log2(e)
  const int qglob = q0 + c;
  const int nkt = (q0 + 15)/32 + 1;
  for (int kt = 0; kt < nkt; ++kt){
    const int kbase = kt*32;
    f32x4 st0 = {0.f,0.f,0.f,0.f}, st1 = {0.f,0.f,0.f,0.f};
    {
      const short* kp = Kbh + (size_t)(kbase + c)*ND + g*8;
      s16x8 ka = *(const s16x8*)kp;
      s16x8 kb = *(const s16x8*)(kp + 32);
      st0 = mfma16(ka, qf[0], st0);
      st0 = mfma16(kb, qf[1], st0);
      const short* kp1 = kp + 16*ND;
      s16x8 kc2 = *(const s16x8*)kp1;
      s16x8 kd = *(const s16x8*)(kp1 + 32);
      st1 = mfma16(kc2, qf[0], st1);
      st1 = mfma16(kd, qf[1], st1);
    }
    float sv[8];
    #pragma unroll
    for (int j=0;j<4;++j){ sv[j] = st0[j]*sc; sv[4+j] = st1[j]*sc; }
    if (kbase + 31 > q0){
      #pragma unroll
      for (int u=0;u<8;++u){
        int kg = kbase + (u>>2)*16 + g*4 + (u&3);   // S^T row = k-local = 4g+j
        if (kg > qglob) sv[u] = -3.0e38f;
      }
    }
    float tm = sv[0];
    #pragma unroll
    for (int u=1;u<8;++u) tm = fmaxf(tm, sv[u]);
    tm = fmaxf(tm, __shfl_xor(tm, 16));
    tm = fmaxf(tm, __shfl_xor(tm, 32));
    float mn = fmaxf(mrow, tm);
    float p[8], tl = 0.f;
    #pragma unroll
    for (int u=0;u<8;++u){ p[u] = __builtin_amdgcn_exp2f(sv[u] - mn); tl += p[u]; }
    tl += __shfl_xor(tl, 16);
    tl += __shfl_xor(tl, 32);
    float alpha = __builtin_amdgcn_exp2f(mrow - mn);
    lrow = lrow*alpha + tl;
    mrow = mn;
    #pragma unroll
    for (int j=0;j<4;++j){
      float aj = __shfl(alpha, g*4 + j);            // alpha for q-local 4g+j lives at lane 4g+j
      #pragma unroll
      for (int dt=0;dt<4;++dt) acc[dt][j] *= aj;
    }
    s16x4 pk0 = { f2bf(p[0]), f2bf(p[1]), f2bf(p[2]), f2bf(p[3]) };
    s16x4 pk1 = { f2bf(p[4]), f2bf(p[5]), f2bf(p[6]), f2bf(p[7]) };
    *(s16x4*)(pw + c*40 + 4*g)      = pk0;          // P[q=c][k=4g+j]
    *(s16x4*)(pw + c*40 + 16 + 4*g) = pk1;          // P[q=c][k=16+4g+j]
    asm volatile("s_waitcnt lgkmcnt(0)" ::: "memory");
    __builtin_amdgcn_sched_barrier(0);
    s16x8 pa = *(const s16x8*)(pw + c*40 + g*8);    // A-frag: P[q=c][k=8g..8g+7]
    #pragma unroll
    for (int dt=0;dt<4;++dt){
      const short* vp = Vbh + (size_t)(dt*16 + c)*NS + kbase + g*8;
      s16x8 vf = *(const s16x8*)vp;
      acc[dt] = mfma16(pa, vf, acc[dt]);
    }
  }
  float invl[4];
  #pragma unroll
  for (int j=0;j<4;++j) invl[j] = 1.f / __shfl(lrow, g*4 + j);
  #pragma unroll
  for (int dt=0;dt<4;++dt){
    #pragma unroll
    for (int j=0;j<4;++j){
      int qr = q0 + g*4 + j;
      Obuf[(size_t)(b*NS + qr)*NE + h*ND + dt*16 + c] = f2bf(acc[dt][j] * invl[j]);
    }
  }
}

extern "C" void kernel_launch(void* const* d_in, const int* in_sizes, int n_in,
                              void* d_out, int out_size, void* d_ws, size_t ws_size,
                              hipStream_t stream)
{
  const float* x     = (const float*)d_in[0];
  const float* w_qkv = (const float*)d_in[1];
  const float* b_qkv = (const float*)d_in[2];
  const float* w_o   = (const float*)d_in[3];
  const float* b_o   = (const float*)d_in[4];
  char* ws = (char*)d_ws;
  const size_t MB = 1u << 20;
  short* Xb    = (short*)(ws);            // 8 MB (reused as Obuf after GEMM1)
  short* Wqkvt = (short*)(ws + 8*MB);     // 6 MB
  short* Wot   = (short*)(ws + 14*MB);    // 2 MB
  short* QKV   = (short*)(ws + 16*MB);    // 24 MB
  short* Qrp   = (short*)(ws + 40*MB);    // 8 MB
  short* Krp   = (short*)(ws + 48*MB);    // 8 MB
  short* Vtp   = (short*)(ws + 56*MB);    // 8 MB  (total 64 MB)

  k_cvt<<<4096, 256, 0, stream>>>(x, Xb, (NB*NS*NE)/4);
  k_tcvt<<<dim3(N3/32, NE/32), dim3(32,8), 0, stream>>>(w_qkv, Wqkvt, NE, N3);
  k_tcvt<<<dim3(NE/32, NE/32), dim3(32,8), 0, stream>>>(w_o, Wot, NE, NE);
  k_gemm<0><<<dim3((NB*NS)/128, N3/128), 256, 0, stream>>>(Xb, Wqkvt, b_qkv, QKV, nullptr,
                                                           NB*NS, N3, NE);
  k_rope<<<(NB*NS*NH*32)/256, 256, 0, stream>>>(QKV, Qrp, Krp);
  k_vtrans<<<NB*NH*(NS/64), 256, 0, stream>>>(QKV, Vtp);
  k_attn<<<NB*NH*(NS/64), 256, 0, stream>>>(Qrp, Krp, Vtp, Xb);
  k_gemm<1><<<dim3((NB*NS)/128, NE/128), 256, 0, stream>>>(Xb, Wot, b_o, nullptr,
                                                           (float*)d_out, NB*NS, NE, NE);
}